// Round 9
// baseline (301.460 us; speedup 1.0000x reference)
//
#include <hip/hip_runtime.h>
#include <hip/hip_bf16.h>
#include <math.h>

#define NRL 4
#define LL 4096
#define NFFT 4104
#define LP 4224
#define NB 64
#define WD 64
#define BST (LP*WD*2)        // 540672 bytes per batch plane
#define LCH 33               // l-chunks of 128
#define PI2 6.28318530717958647692f

typedef __attribute__((ext_vector_type(8))) short short8;
typedef __attribute__((ext_vector_type(4))) float f32x4;

__device__ inline unsigned short f2bf(float f){
  unsigned int u = __float_as_uint(f);
  return (unsigned short)((u + 0x7FFFu + ((u>>16)&1u)) >> 16);
}
// tanh-form gelu: |err vs erf-gelu| <= ~5e-4
__device__ inline float gelu_f(float v){
  float v2 = v*v;
  float z = v * fmaf(0.07135481627f, v2, 1.5957691216f);
  float e = __expf(-z);
  return v * __builtin_amdgcn_rcpf(1.0f + e);
}

// ---- one prologue kernel: tf (1056 blocks) | tif (1056) | conv-w frags (64)
__global__ void k_tables(const float* __restrict__ cw,
                         unsigned short* __restrict__ tf,
                         unsigned short* __restrict__ tif,
                         unsigned short* __restrict__ whi, unsigned short* __restrict__ wlo){
  int bid = blockIdx.x;
  if (bid < 1056){
    int idx = bid*256 + threadIdx.x;          // 270336
    int e = idx & 7; int t = idx >> 3;
    int lane = t & 63; int t2 = t >> 6;
    int js = t2 & 3; int ks = t2 >> 2;
    int l = ks*32 + 8*(lane>>4) + e;
    int j = js*16 + (lane & 15);
    int m = j >> 1;
    float v = 0.f;
    if (l < NFFT){
      int r = (m*l) % NFFT;
      float ang = PI2 * ((float)r / (float)NFFT);
      v = (j & 1) ? -__sinf(ang) : __cosf(ang);
    }
    tf[idx] = f2bf(v);
  } else if (bid < 2112){
    int idx = (bid-1056)*256 + threadIdx.x;   // 270336
    int e = idx & 7; int t = idx >> 3;
    int l = t % LP; int rq = t / LP;
    int q = rq & 3; int ks2 = rq >> 2;
    int j2 = ks2*32 + 8*q + e;
    int m = j2 >> 1;
    float v = 0.f;
    if (l < NFFT){
      int r = (m*l) % NFFT;
      float ang = PI2 * ((float)r / (float)NFFT);
      float inv = 1.0f/(float)NFFT;
      v = (j2 & 1) ? (-2.f*inv*__sinf(ang)) : ((m==0?inv:2.f*inv)*__cosf(ang));
    }
    tif[idx] = f2bf(v);
  } else {
    int idx = (bid-2112)*256 + threadIdx.x;   // 16384
    int e = idx & 7; int lane = (idx>>3)&63; int os = (idx>>9)&3;
    int ks2 = (idx>>11)&1; int ly = idx>>12;
    int k = ks2*32 + 8*(lane>>4) + e;
    int o = os*16 + (lane&15);
    float v = cw[((size_t)(ly*64 + o))*64 + k];
    unsigned short h = f2bf(v);
    float lo = v - __uint_as_float(((unsigned)h)<<16);
    whi[idx] = h; wlo[idx] = f2bf(lo);
  }
}

// ---- fused lift: compute lifted x in regs -> lc plane + LDS transpose ->
//      partial DFT -> atomicAdd into xm (replaces k_lift + k_dft + k_red)
__global__ __launch_bounds__(256) void k_lift2(const float* __restrict__ x,
    const float* __restrict__ lw, const float* __restrict__ lb,
    const unsigned short* __restrict__ tf,
    unsigned short* __restrict__ xh, float* __restrict__ xmout){
  __shared__ __align__(16) unsigned short ldt[64*128];  // swizzled [c][l-l0]
  __shared__ float xs[128];
  int l0 = blockIdx.x*128; int b = blockIdx.y;
  int tid = threadIdx.x;
  int os = tid >> 6, lane = tid & 63, q = lane >> 4, lr = lane & 15;
  if (tid < 32){
    float4 v = make_float4(0.f,0.f,0.f,0.f);
    int l = l0 + tid*4;
    if (l < LL) v = *(const float4*)(x + (size_t)b*LL + l);
    *(float4*)(xs + tid*4) = v;
  }
  __syncthreads();
  float w0[4], w1[4], bb[4];
  #pragma unroll
  for (int r=0;r<4;r++){
    int c = os*16 + 4*q + r;
    w0[r] = lw[2*c]; w1[r] = lw[2*c+1]; bb[r] = lb[c];
  }
  char* nb = (char*)xh + (size_t)b*BST;
  int co = os*32 + 8*q;
  #pragma unroll
  for (int ls=0;ls<8;ls++){
    int lrow = ls*16 + lr; int l = l0 + lrow;
    float g = (float)l * (1.0f/4095.0f);
    unsigned short us[4];
    #pragma unroll
    for (int r=0;r<4;r++){
      float v = (l < LL) ? fmaf(w0[r], xs[lrow], fmaf(w1[r], g, bb[r])) : 0.f;
      us[r] = f2bf(v);
    }
    unsigned int h0 = (unsigned)us[0] | (((unsigned)us[1])<<16);
    unsigned int h1 = (unsigned)us[2] | (((unsigned)us[3])<<16);
    *(uint2*)(nb + (size_t)l*128 + (co ^ ((lrow&7)<<4))) = make_uint2(h0,h1);
    #pragma unroll
    for (int r=0;r<4;r++){
      int c = os*16 + 4*q + r;
      *(unsigned short*)((char*)ldt + c*256 + ((lrow*2) ^ (((4*q+r)&7)<<4))) = us[r];
    }
  }
  __syncthreads();
  f32x4 a2[4];
  #pragma unroll
  for (int js=0;js<4;js++) a2[js] = (f32x4){0.f,0.f,0.f,0.f};
  #pragma unroll
  for (int ks=0;ks<4;ks++){
    short8 av = *(const short8*)((char*)ldt + (os*16+lr)*256 + ((ks*64 + 16*q) ^ ((lr&7)<<4)));
    #pragma unroll
    for (int js=0;js<4;js++){
      short8 bv = *(const short8*)(tf + ((size_t)(((blockIdx.x*4 + ks)*4 + js)*64 + lane))*8);
      a2[js] = __builtin_amdgcn_mfma_f32_16x16x32_bf16(av, bv, a2[js], 0,0,0);
    }
  }
  float* xp = xmout + (size_t)b*4096;
  #pragma unroll
  for (int js=0;js<4;js++){
    #pragma unroll
    for (int r=0;r<4;r++)
      atomicAdd(&xp[(os*16 + 4*q + r)*64 + js*16 + lr], a2[js][r]);
  }
}

// ---- mode mix -> om A-operand frags [b][ks2 2][os 4][lane 64][e 8] hi/lo
__global__ void k_mix(const float* __restrict__ xm, const float* __restrict__ wr,
                      const float* __restrict__ wi,
                      unsigned short* __restrict__ mh, unsigned short* __restrict__ ml){
  int idx = blockIdx.x*256 + threadIdx.x;     // 131072
  int m = idx & 31, o = (idx>>5)&63, b = idx>>11;
  const float* xp = xm + ((size_t)(b*64))*64 + 2*m;
  float ar=0.f, ai=0.f;
  for (int i=0;i<64;i++){
    float xr = xp[i*64], xi = xp[i*64+1];
    float wrv = wr[((size_t)(i*64 + o))*32 + m];
    float wiv = wi[((size_t)(i*64 + o))*32 + m];
    ar = fmaf(xr,wrv,ar); ar = fmaf(-xi,wiv,ar);
    ai = fmaf(xr,wiv,ai); ai = fmaf(xi,wrv,ai);
  }
  int j2 = 2*m;
  int ks2 = j2 >> 5, rem = j2 & 31, q = rem >> 3, e = rem & 7;
  int lane = q*16 + (o & 15), os = o >> 4;
  size_t a = ((size_t)(((b*2 + ks2)*4 + os)*64 + lane))*8 + e;
  unsigned short hr = f2bf(ar), hi_ = f2bf(ai);
  float lr_ = ar - __uint_as_float(((unsigned)hr)<<16);
  float li_ = ai - __uint_as_float(((unsigned)hi_)<<16);
  *(ushort2*)(mh + a) = make_ushort2(hr, hi_);
  *(ushort2*)(ml + a) = make_ushort2(f2bf(lr_), f2bf(li_));
}

// ---- fused layer: conv+spectral MFMA, direct stores, fused partial DFT
//      accumulated via atomicAdd into next layer's xm
__global__ __launch_bounds__(256) void k_layer(
    const unsigned short* __restrict__ xlc,
    const unsigned short* __restrict__ wfch, const unsigned short* __restrict__ wfcl,
    const unsigned short* __restrict__ wmh, const unsigned short* __restrict__ wml,
    const unsigned short* __restrict__ tif, const unsigned short* __restrict__ tf,
    const float* __restrict__ cb,
    unsigned short* __restrict__ xnh, float* __restrict__ xmout,
    float* __restrict__ dout, int last){
  __shared__ __align__(16) unsigned short ldt[64*128];  // swizzled [c][l-l0]
  int l0 = blockIdx.x * 128; int b = blockIdx.y;
  int tid = threadIdx.x;
  int os = tid >> 6, lane = tid & 63, q = lane >> 4, lr = lane & 15;
  const char* xb = (const char*)xlc + (size_t)b*BST;

  short8 ch_[2], cl_[2], mh_[2], ml_[2];
  #pragma unroll
  for (int ks=0;ks<2;ks++){
    size_t a = ((size_t)((ks*4 + os)*64 + lane))*8;
    ch_[ks] = *(const short8*)(wfch + a);
    cl_[ks] = *(const short8*)(wfcl + a);
    size_t am = ((size_t)(((b*2 + ks)*4 + os)*64 + lane))*8;
    mh_[ks] = *(const short8*)(wmh + am);
    ml_[ks] = *(const short8*)(wml + am);
  }
  f32x4 acc[8];
  #pragma unroll
  for (int ls=0;ls<8;ls++) acc[ls] = (f32x4){0.f,0.f,0.f,0.f};
  int sw = (lr & 7) << 4;
  #pragma unroll
  for (int ks=0;ks<2;ks++){
    int cofs = (64*ks + 16*q) ^ sw;
    #pragma unroll
    for (int ls=0;ls<8;ls++){
      short8 bh = *(const short8*)(xb + (size_t)(l0 + ls*16 + lr)*128 + cofs);
      acc[ls] = __builtin_amdgcn_mfma_f32_16x16x32_bf16(ch_[ks], bh, acc[ls], 0,0,0);
      acc[ls] = __builtin_amdgcn_mfma_f32_16x16x32_bf16(cl_[ks], bh, acc[ls], 0,0,0);
    }
  }
  #pragma unroll
  for (int ks=0;ks<2;ks++){
    #pragma unroll
    for (int ls=0;ls<8;ls++){
      int l = l0 + ls*16 + lr;
      short8 bt = *(const short8*)(tif + ((size_t)((ks*4 + q)*LP + l))*8);
      acc[ls] = __builtin_amdgcn_mfma_f32_16x16x32_bf16(mh_[ks], bt, acc[ls], 0,0,0);
      acc[ls] = __builtin_amdgcn_mfma_f32_16x16x32_bf16(ml_[ks], bt, acc[ls], 0,0,0);
    }
  }
  float bias[4];
  #pragma unroll
  for (int r=0;r<4;r++) bias[r] = cb[os*16 + 4*q + r];

  if (!last){
    int co = os*32 + 8*q;
    char* nb = (char*)xnh + (size_t)b*BST;
    #pragma unroll
    for (int ls=0;ls<8;ls++){
      int lrow = ls*16 + lr; int l = l0 + lrow;
      unsigned short us[4];
      #pragma unroll
      for (int r=0;r<4;r++)
        us[r] = (l < NFFT) ? f2bf(gelu_f(acc[ls][r] + bias[r])) : (unsigned short)0;
      if (l < NFFT){
        unsigned int h0 = (unsigned)us[0] | (((unsigned)us[1])<<16);
        unsigned int h1 = (unsigned)us[2] | (((unsigned)us[3])<<16);
        *(uint2*)(nb + (size_t)l*128 + (co ^ ((lrow&7)<<4))) = make_uint2(h0,h1);
      }
      #pragma unroll
      for (int r=0;r<4;r++){
        int c = os*16 + 4*q + r;
        *(unsigned short*)((char*)ldt + c*256 + ((lrow*2) ^ (((4*q+r)&7)<<4))) = us[r];
      }
    }
    __syncthreads();
    f32x4 a2[4];
    #pragma unroll
    for (int js=0;js<4;js++) a2[js] = (f32x4){0.f,0.f,0.f,0.f};
    #pragma unroll
    for (int ks=0;ks<4;ks++){
      short8 av = *(const short8*)((char*)ldt + (os*16+lr)*256 + ((ks*64 + 16*q) ^ ((lr&7)<<4)));
      #pragma unroll
      for (int js=0;js<4;js++){
        short8 bv = *(const short8*)(tf + ((size_t)(((blockIdx.x*4 + ks)*4 + js)*64 + lane))*8);
        a2[js] = __builtin_amdgcn_mfma_f32_16x16x32_bf16(av, bv, a2[js], 0,0,0);
      }
    }
    float* xp = xmout + (size_t)b*4096;
    #pragma unroll
    for (int js=0;js<4;js++){
      #pragma unroll
      for (int r=0;r<4;r++)
        atomicAdd(&xp[(os*16 + 4*q + r)*64 + js*16 + lr], a2[js][r]);
    }
  } else {
    #pragma unroll
    for (int ls=0;ls<8;ls++){
      int l = l0 + ls*16 + lr;
      if (l < LL){
        #pragma unroll
        for (int r=0;r<4;r++){
          int o = os*16 + 4*q + r;
          dout[((size_t)(b*64 + o))*LL + l] = acc[ls][r] + bias[r];
        }
      }
    }
  }
}

extern "C" void kernel_launch(void* const* d_in, const int* in_sizes, int n_in,
                              void* d_out, int out_size, void* d_ws, size_t ws_size,
                              hipStream_t stream) {
  const float* x   = (const float*)d_in[0];
  const float* lw  = (const float*)d_in[1];
  const float* lb  = (const float*)d_in[2];
  const float* cw  = (const float*)d_in[3];
  const float* cb  = (const float*)d_in[4];
  const float* swr = (const float*)d_in[5];
  const float* swi = (const float*)d_in[6];

  char* ws = (char*)d_ws;
  size_t PL = (size_t)NB*BST;                 // 34,603,008 bytes per plane
  unsigned short* x0lc = (unsigned short*)(ws);
  unsigned short* x1lc = (unsigned short*)(ws + PL);
  unsigned short* tf   = (unsigned short*)(ws + 2*PL);
  unsigned short* tif  = (unsigned short*)(ws + 2*PL + 540672);
  unsigned short* wfch = (unsigned short*)(ws + 2*PL + 2*540672);
  unsigned short* wfcl = (unsigned short*)(ws + 2*PL + 2*540672 + 32768);
  unsigned short* wmh  = (unsigned short*)(ws + 2*PL + 2*540672 + 2*32768);
  unsigned short* wml  = (unsigned short*)(ws + 2*PL + 2*540672 + 2*32768 + 524288);
  float*          xmA  = (float*)        (ws + 2*PL + 2*540672 + 2*32768 + 2*524288);
  float*          xmB  = xmA + 262144;        // 1 MB each (64b x 64c x 64j f32)

  hipMemsetAsync(xmA, 0, 2*262144*sizeof(float), stream);   // zero both xm buffers

  k_tables<<<2176, 256,0,stream>>>(cw, tf, tif, wfch, wfcl);
  k_lift2 <<<dim3(LCH,NB),256,0,stream>>>(x, lw, lb, tf, x0lc, xmA);

  for (int k=0;k<NRL;k++){
    unsigned short* curlc = (k&1) ? x1lc : x0lc;
    unsigned short* nxtlc = (k&1) ? x0lc : x1lc;
    float* xsrc = (k&1) ? xmB : xmA;            // mix input for layer k
    float* xdst = (k&1) ? xmA : xmB;            // layer k accumulates next layer's modes
    if (k >= 2)  // xdst was consumed by mix(k-1); re-zero before accumulating
      hipMemsetAsync(xdst, 0, 262144*sizeof(float), stream);
    k_mix<<<512, 256,0,stream>>>(xsrc, swr + (size_t)k*131072, swi + (size_t)k*131072, wmh, wml);
    k_layer<<<dim3(LCH,NB),256,0,stream>>>(curlc,
        wfch + (size_t)k*4096, wfcl + (size_t)k*4096, wmh, wml, tif, tf,
        cb + (size_t)k*64, nxtlc, xdst, (float*)d_out, (k==NRL-1) ? 1 : 0);
  }
}

// Round 10
// 282.596 us; speedup vs baseline: 1.0668x; 1.0668x over previous
//
#include <hip/hip_runtime.h>
#include <hip/hip_bf16.h>
#include <math.h>

#define NRL 4
#define LL 4096
#define NFFT 4104
#define LP 4224
#define NB 64
#define WD 64
#define BST (LP*WD*2)        // 540672 bytes per batch plane
#define LB2 17               // blocks in l (each covers up to 2x128)
#define PCH 17               // partial chunks
#define PI2 6.28318530717958647692f

typedef __attribute__((ext_vector_type(8))) short short8;
typedef __attribute__((ext_vector_type(4))) float f32x4;
typedef __attribute__((ext_vector_type(2))) float f32x2;

__device__ inline unsigned short f2bf(float f){
  unsigned int u = __float_as_uint(f);
  return (unsigned short)((u + 0x7FFFu + ((u>>16)&1u)) >> 16);
}
// tanh-form gelu: |err vs erf-gelu| <= ~5e-4
__device__ inline float gelu_f(float v){
  float v2 = v*v;
  float z = v * fmaf(0.07135481627f, v2, 1.5957691216f);
  float e = __expf(-z);
  return v * __builtin_amdgcn_rcpf(1.0f + e);
}

// ---- one prologue kernel: tf (1056 blocks) | tif (1056) | conv-w frags (64)
__global__ void k_tables(const float* __restrict__ cw,
                         unsigned short* __restrict__ tf,
                         unsigned short* __restrict__ tif,
                         unsigned short* __restrict__ whi, unsigned short* __restrict__ wlo){
  int bid = blockIdx.x;
  if (bid < 1056){
    int idx = bid*256 + threadIdx.x;          // 270336
    int e = idx & 7; int t = idx >> 3;
    int lane = t & 63; int t2 = t >> 6;
    int js = t2 & 3; int ks = t2 >> 2;
    int l = ks*32 + 8*(lane>>4) + e;
    int j = js*16 + (lane & 15);
    int m = j >> 1;
    float v = 0.f;
    if (l < NFFT){
      int r = (m*l) % NFFT;
      float ang = PI2 * ((float)r / (float)NFFT);
      v = (j & 1) ? -__sinf(ang) : __cosf(ang);
    }
    tf[idx] = f2bf(v);
  } else if (bid < 2112){
    int idx = (bid-1056)*256 + threadIdx.x;   // 270336
    int e = idx & 7; int t = idx >> 3;
    int l = t % LP; int rq = t / LP;
    int q = rq & 3; int ks2 = rq >> 2;
    int j2 = ks2*32 + 8*q + e;
    int m = j2 >> 1;
    float v = 0.f;
    if (l < NFFT){
      int r = (m*l) % NFFT;
      float ang = PI2 * ((float)r / (float)NFFT);
      float inv = 1.0f/(float)NFFT;
      v = (j2 & 1) ? (-2.f*inv*__sinf(ang)) : ((m==0?inv:2.f*inv)*__cosf(ang));
    }
    tif[idx] = f2bf(v);
  } else {
    int idx = (bid-2112)*256 + threadIdx.x;   // 16384
    int e = idx & 7; int lane = (idx>>3)&63; int os = (idx>>9)&3;
    int ks2 = (idx>>11)&1; int ly = idx>>12;
    int k = ks2*32 + 8*(lane>>4) + e;
    int o = os*16 + (lane&15);
    float v = cw[((size_t)(ly*64 + o))*64 + k];
    unsigned short h = f2bf(v);
    float lo = v - __uint_as_float(((unsigned)h)<<16);
    whi[idx] = h; wlo[idx] = f2bf(lo);
  }
}

// ---- fused lift: lifted x -> lc plane + LDS transpose -> partial DFT chunks
__global__ __launch_bounds__(256) void k_lift2(const float* __restrict__ x,
    const float* __restrict__ lw, const float* __restrict__ lb,
    const unsigned short* __restrict__ tf,
    unsigned short* __restrict__ xh, float* __restrict__ xmout){
  __shared__ __align__(16) unsigned short ldt[64*128];  // swizzled [c][l-l0]
  __shared__ float xs[128];
  int b = blockIdx.y;
  int tid = threadIdx.x;
  int os = tid >> 6, lane = tid & 63, q = lane >> 4, lr = lane & 15;
  float w0[4], w1[4], bb[4];
  #pragma unroll
  for (int r=0;r<4;r++){
    int c = os*16 + 4*q + r;
    w0[r] = lw[2*c]; w1[r] = lw[2*c+1]; bb[r] = lb[c];
  }
  char* nb = (char*)xh + (size_t)b*BST;
  int co = os*32 + 8*q;
  f32x4 a2[4];
  #pragma unroll
  for (int js=0;js<4;js++) a2[js] = (f32x4){0.f,0.f,0.f,0.f};
  #pragma unroll 1
  for (int h=0; h<2; h++){
    int l0 = (blockIdx.x*2 + h)*128;
    if (l0 >= LP) break;
    if (tid < 32){
      float4 v = make_float4(0.f,0.f,0.f,0.f);
      int l = l0 + tid*4;
      if (l < LL) v = *(const float4*)(x + (size_t)b*LL + l);
      *(float4*)(xs + tid*4) = v;
    }
    __syncthreads();
    #pragma unroll
    for (int ls=0;ls<8;ls++){
      int lrow = ls*16 + lr; int l = l0 + lrow;
      float g = (float)l * (1.0f/4095.0f);
      unsigned short us[4];
      #pragma unroll
      for (int r=0;r<4;r++){
        float v = (l < LL) ? fmaf(w0[r], xs[lrow], fmaf(w1[r], g, bb[r])) : 0.f;
        us[r] = f2bf(v);
      }
      unsigned int h0 = (unsigned)us[0] | (((unsigned)us[1])<<16);
      unsigned int h1 = (unsigned)us[2] | (((unsigned)us[3])<<16);
      *(uint2*)(nb + (size_t)l*128 + (co ^ ((lrow&7)<<4))) = make_uint2(h0,h1);
      #pragma unroll
      for (int r=0;r<4;r++){
        int c = os*16 + 4*q + r;
        *(unsigned short*)((char*)ldt + c*256 + ((lrow*2) ^ ((c&7)<<4))) = us[r];
      }
    }
    __syncthreads();
    #pragma unroll
    for (int ks=0;ks<4;ks++){
      short8 av = *(const short8*)((char*)ldt + (os*16+lr)*256 + ((ks*64 + 16*q) ^ ((lr&7)<<4)));
      #pragma unroll
      for (int js=0;js<4;js++){
        short8 bv = *(const short8*)(tf + ((size_t)(((((blockIdx.x*2+h)*4 + ks)*4) + js)*64 + lane))*8);
        a2[js] = __builtin_amdgcn_mfma_f32_16x16x32_bf16(av, bv, a2[js], 0,0,0);
      }
    }
    __syncthreads();
  }
  float* pp = xmout + ((size_t)blockIdx.x*64 + b)*4096;
  #pragma unroll
  for (int js=0;js<4;js++){
    #pragma unroll
    for (int r=0;r<4;r++)
      pp[(os*16 + 4*q + r)*64 + js*16 + lr] = a2[js][r];
  }
}

// ---- reduce 17 partial chunks -> xm, float2 coalesced (512 blocks)
__global__ void k_red(const float* __restrict__ xmp, float* __restrict__ xm){
  int i2 = blockIdx.x*256 + threadIdx.x;      // 131072
  f32x2 s = (f32x2){0.f,0.f};
  #pragma unroll
  for (int p=0;p<PCH;p++){
    f32x2 v = *(const f32x2*)(xmp + (size_t)p*262144 + (size_t)i2*2);
    s.x += v.x; s.y += v.y;
  }
  *(f32x2*)(xm + (size_t)i2*2) = s;
}

// ---- mode mix -> om A-operand frags [b][ks2 2][os 4][lane 64][e 8] hi/lo
__global__ void k_mix(const float* __restrict__ xm, const float* __restrict__ wr,
                      const float* __restrict__ wi,
                      unsigned short* __restrict__ mh, unsigned short* __restrict__ ml){
  int idx = blockIdx.x*256 + threadIdx.x;     // 131072
  int m = idx & 31, o = (idx>>5)&63, b = idx>>11;
  const float* xp = xm + ((size_t)(b*64))*64 + 2*m;
  float ar=0.f, ai=0.f;
  for (int i=0;i<64;i++){
    float xr = xp[i*64], xi = xp[i*64+1];
    float wrv = wr[((size_t)(i*64 + o))*32 + m];
    float wiv = wi[((size_t)(i*64 + o))*32 + m];
    ar = fmaf(xr,wrv,ar); ar = fmaf(-xi,wiv,ar);
    ai = fmaf(xr,wiv,ai); ai = fmaf(xi,wrv,ai);
  }
  int j2 = 2*m;
  int ks2 = j2 >> 5, rem = j2 & 31, q = rem >> 3, e = rem & 7;
  int lane = q*16 + (o & 15), os = o >> 4;
  size_t a = ((size_t)(((b*2 + ks2)*4 + os)*64 + lane))*8 + e;
  unsigned short hr = f2bf(ar), hi_ = f2bf(ai);
  float lr_ = ar - __uint_as_float(((unsigned)hr)<<16);
  float li_ = ai - __uint_as_float(((unsigned)hi_)<<16);
  *(ushort2*)(mh + a) = make_ushort2(hr, hi_);
  *(ushort2*)(ml + a) = make_ushort2(f2bf(lr_), f2bf(li_));
}

// ---- fused layer: 2x128-l passes, conv+spectral MFMA, direct stores,
//      fused partial DFT accumulated in regs, one partial store per block
__global__ __launch_bounds__(256) void k_layer(
    const unsigned short* __restrict__ xlc,
    const unsigned short* __restrict__ wfch, const unsigned short* __restrict__ wfcl,
    const unsigned short* __restrict__ wmh, const unsigned short* __restrict__ wml,
    const unsigned short* __restrict__ tif, const unsigned short* __restrict__ tf,
    const float* __restrict__ cb,
    unsigned short* __restrict__ xnh, float* __restrict__ xmout,
    float* __restrict__ dout, int last){
  __shared__ __align__(16) unsigned short ldt[64*128];  // swizzled [c][l-l0]
  int b = blockIdx.y;
  int tid = threadIdx.x;
  int os = tid >> 6, lane = tid & 63, q = lane >> 4, lr = lane & 15;
  const char* xb = (const char*)xlc + (size_t)b*BST;

  short8 ch_[2], cl_[2], mh_[2], ml_[2];
  #pragma unroll
  for (int ks=0;ks<2;ks++){
    size_t a = ((size_t)((ks*4 + os)*64 + lane))*8;
    ch_[ks] = *(const short8*)(wfch + a);
    cl_[ks] = *(const short8*)(wfcl + a);
    size_t am = ((size_t)(((b*2 + ks)*4 + os)*64 + lane))*8;
    mh_[ks] = *(const short8*)(wmh + am);
    ml_[ks] = *(const short8*)(wml + am);
  }
  float bias[4];
  #pragma unroll
  for (int r=0;r<4;r++) bias[r] = cb[os*16 + 4*q + r];
  int sw = (lr & 7) << 4;
  f32x4 a2[4];
  #pragma unroll
  for (int js=0;js<4;js++) a2[js] = (f32x4){0.f,0.f,0.f,0.f};

  #pragma unroll 1
  for (int h=0; h<2; h++){
    int l0 = (blockIdx.x*2 + h)*128;
    if (l0 >= LP) break;
    f32x4 acc[8];
    #pragma unroll
    for (int ls=0;ls<8;ls++) acc[ls] = (f32x4){0.f,0.f,0.f,0.f};
    #pragma unroll
    for (int ks=0;ks<2;ks++){
      int cofs = (64*ks + 16*q) ^ sw;
      short8 bh8[8];
      #pragma unroll
      for (int ls=0;ls<8;ls++)
        bh8[ls] = *(const short8*)(xb + (size_t)(l0 + ls*16 + lr)*128 + cofs);
      #pragma unroll
      for (int ls=0;ls<8;ls++){
        acc[ls] = __builtin_amdgcn_mfma_f32_16x16x32_bf16(ch_[ks], bh8[ls], acc[ls], 0,0,0);
        acc[ls] = __builtin_amdgcn_mfma_f32_16x16x32_bf16(cl_[ks], bh8[ls], acc[ls], 0,0,0);
      }
    }
    #pragma unroll
    for (int ks=0;ks<2;ks++){
      short8 bt8[8];
      #pragma unroll
      for (int ls=0;ls<8;ls++)
        bt8[ls] = *(const short8*)(tif + ((size_t)((ks*4 + q)*LP + l0 + ls*16 + lr))*8);
      #pragma unroll
      for (int ls=0;ls<8;ls++){
        acc[ls] = __builtin_amdgcn_mfma_f32_16x16x32_bf16(mh_[ks], bt8[ls], acc[ls], 0,0,0);
        acc[ls] = __builtin_amdgcn_mfma_f32_16x16x32_bf16(ml_[ks], bt8[ls], acc[ls], 0,0,0);
      }
    }

    if (!last){
      int co = os*32 + 8*q;
      char* nb = (char*)xnh + (size_t)b*BST;
      #pragma unroll
      for (int ls=0;ls<8;ls++){
        int lrow = ls*16 + lr; int l = l0 + lrow;
        unsigned short us[4];
        #pragma unroll
        for (int r=0;r<4;r++)
          us[r] = (l < NFFT) ? f2bf(gelu_f(acc[ls][r] + bias[r])) : (unsigned short)0;
        if (l < NFFT){
          unsigned int h0 = (unsigned)us[0] | (((unsigned)us[1])<<16);
          unsigned int h1 = (unsigned)us[2] | (((unsigned)us[3])<<16);
          *(uint2*)(nb + (size_t)l*128 + (co ^ ((lrow&7)<<4))) = make_uint2(h0,h1);
        }
        #pragma unroll
        for (int r=0;r<4;r++){
          int c = os*16 + 4*q + r;
          *(unsigned short*)((char*)ldt + c*256 + ((lrow*2) ^ ((c&7)<<4))) = us[r];
        }
      }
      __syncthreads();
      #pragma unroll
      for (int ks=0;ks<4;ks++){
        short8 av = *(const short8*)((char*)ldt + (os*16+lr)*256 + ((ks*64 + 16*q) ^ ((lr&7)<<4)));
        #pragma unroll
        for (int js=0;js<4;js++){
          short8 bv = *(const short8*)(tf + ((size_t)(((((blockIdx.x*2+h)*4 + ks)*4) + js)*64 + lane))*8);
          a2[js] = __builtin_amdgcn_mfma_f32_16x16x32_bf16(av, bv, a2[js], 0,0,0);
        }
      }
      __syncthreads();
    } else {
      #pragma unroll
      for (int ls=0;ls<8;ls++){
        int l = l0 + ls*16 + lr;
        if (l < LL){
          #pragma unroll
          for (int r=0;r<4;r++){
            int o = os*16 + 4*q + r;
            dout[((size_t)(b*64 + o))*LL + l] = acc[ls][r] + bias[r];
          }
        }
      }
    }
  }
  if (!last){
    float* pp = xmout + ((size_t)blockIdx.x*64 + b)*4096;
    #pragma unroll
    for (int js=0;js<4;js++){
      #pragma unroll
      for (int r=0;r<4;r++)
        pp[(os*16 + 4*q + r)*64 + js*16 + lr] = a2[js][r];
    }
  }
}

extern "C" void kernel_launch(void* const* d_in, const int* in_sizes, int n_in,
                              void* d_out, int out_size, void* d_ws, size_t ws_size,
                              hipStream_t stream) {
  const float* x   = (const float*)d_in[0];
  const float* lw  = (const float*)d_in[1];
  const float* lb  = (const float*)d_in[2];
  const float* cw  = (const float*)d_in[3];
  const float* cb  = (const float*)d_in[4];
  const float* swr = (const float*)d_in[5];
  const float* swi = (const float*)d_in[6];

  char* ws = (char*)d_ws;
  size_t PL = (size_t)NB*BST;                 // 34,603,008 bytes per plane
  unsigned short* x0lc = (unsigned short*)(ws);
  unsigned short* x1lc = (unsigned short*)(ws + PL);
  unsigned short* tf   = (unsigned short*)(ws + 2*PL);
  unsigned short* tif  = (unsigned short*)(ws + 2*PL + 540672);
  unsigned short* wfch = (unsigned short*)(ws + 2*PL + 2*540672);
  unsigned short* wfcl = (unsigned short*)(ws + 2*PL + 2*540672 + 32768);
  unsigned short* wmh  = (unsigned short*)(ws + 2*PL + 2*540672 + 2*32768);
  unsigned short* wml  = (unsigned short*)(ws + 2*PL + 2*540672 + 2*32768 + 524288);
  float*          xm   = (float*)        (ws + 2*PL + 2*540672 + 2*32768 + 2*524288);
  float*          pA   = xm + 262144;         // 17 x 1MB partial chunks
  float*          pB   = pA + (size_t)PCH*262144;

  k_tables<<<2176, 256,0,stream>>>(cw, tf, tif, wfch, wfcl);
  k_lift2 <<<dim3(LB2,NB),256,0,stream>>>(x, lw, lb, tf, x0lc, pA);

  for (int k=0;k<NRL;k++){
    unsigned short* curlc = (k&1) ? x1lc : x0lc;
    unsigned short* nxtlc = (k&1) ? x0lc : x1lc;
    float* psrc = (k&1) ? pB : pA;
    float* pdst = (k&1) ? pA : pB;
    k_red<<<512, 256,0,stream>>>(psrc, xm);
    k_mix<<<512, 256,0,stream>>>(xm, swr + (size_t)k*131072, swi + (size_t)k*131072, wmh, wml);
    k_layer<<<dim3(LB2,NB),256,0,stream>>>(curlc,
        wfch + (size_t)k*4096, wfcl + (size_t)k*4096, wmh, wml, tif, tf,
        cb + (size_t)k*64, nxtlc, pdst, (float*)d_out, (k==NRL-1) ? 1 : 0);
  }
}

// Round 11
// 259.453 us; speedup vs baseline: 1.1619x; 1.0892x over previous
//
#include <hip/hip_runtime.h>
#include <hip/hip_bf16.h>
#include <math.h>

#define NRL 4
#define LL 4096
#define NFFT 4104
#define LP 4224
#define NB 64
#define WD 64
#define BST (LP*WD*2)        // 540672 bytes per batch plane
#define LCH 33               // l-chunks of 128
#define PCH 33               // partial chunks
#define PI2 6.28318530717958647692f

typedef __attribute__((ext_vector_type(8))) short short8;
typedef __attribute__((ext_vector_type(4))) float f32x4;
typedef __attribute__((ext_vector_type(2))) float f32x2;

__device__ inline unsigned short f2bf(float f){
  unsigned int u = __float_as_uint(f);
  return (unsigned short)((u + 0x7FFFu + ((u>>16)&1u)) >> 16);
}
// tanh-form gelu: |err vs erf-gelu| <= ~5e-4
__device__ inline float gelu_f(float v){
  float v2 = v*v;
  float z = v * fmaf(0.07135481627f, v2, 1.5957691216f);
  float e = __expf(-z);
  return v * __builtin_amdgcn_rcpf(1.0f + e);
}

// ---- one prologue kernel: tf (1056 blocks) | tif (1056) | conv-w frags (64)
__global__ void k_tables(const float* __restrict__ cw,
                         unsigned short* __restrict__ tf,
                         unsigned short* __restrict__ tif,
                         unsigned short* __restrict__ whi, unsigned short* __restrict__ wlo){
  int bid = blockIdx.x;
  if (bid < 1056){
    int idx = bid*256 + threadIdx.x;          // 270336
    int e = idx & 7; int t = idx >> 3;
    int lane = t & 63; int t2 = t >> 6;
    int js = t2 & 3; int ks = t2 >> 2;
    int l = ks*32 + 8*(lane>>4) + e;
    int j = js*16 + (lane & 15);
    int m = j >> 1;
    float v = 0.f;
    if (l < NFFT){
      int r = (m*l) % NFFT;
      float ang = PI2 * ((float)r / (float)NFFT);
      v = (j & 1) ? -__sinf(ang) : __cosf(ang);
    }
    tf[idx] = f2bf(v);
  } else if (bid < 2112){
    int idx = (bid-1056)*256 + threadIdx.x;   // 270336
    int e = idx & 7; int t = idx >> 3;
    int l = t % LP; int rq = t / LP;
    int q = rq & 3; int ks2 = rq >> 2;
    int j2 = ks2*32 + 8*q + e;
    int m = j2 >> 1;
    float v = 0.f;
    if (l < NFFT){
      int r = (m*l) % NFFT;
      float ang = PI2 * ((float)r / (float)NFFT);
      float inv = 1.0f/(float)NFFT;
      v = (j2 & 1) ? (-2.f*inv*__sinf(ang)) : ((m==0?inv:2.f*inv)*__cosf(ang));
    }
    tif[idx] = f2bf(v);
  } else {
    int idx = (bid-2112)*256 + threadIdx.x;   // 16384
    int e = idx & 7; int lane = (idx>>3)&63; int os = (idx>>9)&3;
    int ks2 = (idx>>11)&1; int ly = idx>>12;
    int k = ks2*32 + 8*(lane>>4) + e;
    int o = os*16 + (lane&15);
    float v = cw[((size_t)(ly*64 + o))*64 + k];
    unsigned short h = f2bf(v);
    float lo = v - __uint_as_float(((unsigned)h)<<16);
    whi[idx] = h; wlo[idx] = f2bf(lo);
  }
}

// ---- fused lift: lifted x -> lc plane + LDS transpose -> partial DFT chunk
__global__ __launch_bounds__(256) void k_lift2(const float* __restrict__ x,
    const float* __restrict__ lw, const float* __restrict__ lb,
    const unsigned short* __restrict__ tf,
    unsigned short* __restrict__ xh, float* __restrict__ xmout){
  __shared__ __align__(16) unsigned short ldt[64*128];  // swizzled [c][l-l0]
  __shared__ float xs[128];
  int l0 = blockIdx.x*128; int b = blockIdx.y;
  int tid = threadIdx.x;
  int os = tid >> 6, lane = tid & 63, q = lane >> 4, lr = lane & 15;
  if (tid < 32){
    float4 v = make_float4(0.f,0.f,0.f,0.f);
    int l = l0 + tid*4;
    if (l < LL) v = *(const float4*)(x + (size_t)b*LL + l);
    *(float4*)(xs + tid*4) = v;
  }
  __syncthreads();
  float w0[4], w1[4], bb[4];
  #pragma unroll
  for (int r=0;r<4;r++){
    int c = os*16 + 4*q + r;
    w0[r] = lw[2*c]; w1[r] = lw[2*c+1]; bb[r] = lb[c];
  }
  char* nb = (char*)xh + (size_t)b*BST;
  int co = os*32 + 8*q;
  #pragma unroll
  for (int ls=0;ls<8;ls++){
    int lrow = ls*16 + lr; int l = l0 + lrow;
    float g = (float)l * (1.0f/4095.0f);
    unsigned short us[4];
    #pragma unroll
    for (int r=0;r<4;r++){
      float v = (l < LL) ? fmaf(w0[r], xs[lrow], fmaf(w1[r], g, bb[r])) : 0.f;
      us[r] = f2bf(v);
    }
    unsigned int h0 = (unsigned)us[0] | (((unsigned)us[1])<<16);
    unsigned int h1 = (unsigned)us[2] | (((unsigned)us[3])<<16);
    *(uint2*)(nb + (size_t)l*128 + (co ^ ((lrow&7)<<4))) = make_uint2(h0,h1);
    #pragma unroll
    for (int r=0;r<4;r++){
      int c = os*16 + 4*q + r;
      *(unsigned short*)((char*)ldt + c*256 + ((lrow*2) ^ ((c&7)<<4))) = us[r];
    }
  }
  __syncthreads();
  f32x4 a2[4];
  #pragma unroll
  for (int js=0;js<4;js++) a2[js] = (f32x4){0.f,0.f,0.f,0.f};
  #pragma unroll
  for (int ks=0;ks<4;ks++){
    short8 av = *(const short8*)((char*)ldt + (os*16+lr)*256 + ((ks*64 + 16*q) ^ ((lr&7)<<4)));
    #pragma unroll
    for (int js=0;js<4;js++){
      short8 bv = *(const short8*)(tf + ((size_t)(((blockIdx.x*4 + ks)*4 + js)*64 + lane))*8);
      a2[js] = __builtin_amdgcn_mfma_f32_16x16x32_bf16(av, bv, a2[js], 0,0,0);
    }
  }
  float* pp = xmout + ((size_t)blockIdx.x*64 + b)*4096;
  #pragma unroll
  for (int js=0;js<4;js++){
    #pragma unroll
    for (int r=0;r<4;r++)
      pp[(os*16 + 4*q + r)*64 + js*16 + lr] = a2[js][r];
  }
}

// ---- reduce 33 partial chunks -> xm, float2 coalesced (512 blocks)
__global__ void k_red(const float* __restrict__ xmp, float* __restrict__ xm){
  int i2 = blockIdx.x*256 + threadIdx.x;      // 131072
  f32x2 s = (f32x2){0.f,0.f};
  #pragma unroll 3
  for (int p=0;p<PCH;p++){
    f32x2 v = *(const f32x2*)(xmp + (size_t)p*262144 + (size_t)i2*2);
    s.x += v.x; s.y += v.y;
  }
  *(f32x2*)(xm + (size_t)i2*2) = s;
}

// ---- mode mix -> om A-operand frags [b][ks2 2][os 4][lane 64][e 8] hi/lo
__global__ void k_mix(const float* __restrict__ xm, const float* __restrict__ wr,
                      const float* __restrict__ wi,
                      unsigned short* __restrict__ mh, unsigned short* __restrict__ ml){
  int idx = blockIdx.x*256 + threadIdx.x;     // 131072
  int m = idx & 31, o = (idx>>5)&63, b = idx>>11;
  const float* xp = xm + ((size_t)(b*64))*64 + 2*m;
  float ar=0.f, ai=0.f;
  for (int i=0;i<64;i++){
    float xr = xp[i*64], xi = xp[i*64+1];
    float wrv = wr[((size_t)(i*64 + o))*32 + m];
    float wiv = wi[((size_t)(i*64 + o))*32 + m];
    ar = fmaf(xr,wrv,ar); ar = fmaf(-xi,wiv,ar);
    ai = fmaf(xr,wiv,ai); ai = fmaf(xi,wrv,ai);
  }
  int j2 = 2*m;
  int ks2 = j2 >> 5, rem = j2 & 31, q = rem >> 3, e = rem & 7;
  int lane = q*16 + (o & 15), os = o >> 4;
  size_t a = ((size_t)(((b*2 + ks2)*4 + os)*64 + lane))*8 + e;
  unsigned short hr = f2bf(ar), hi_ = f2bf(ai);
  float lr_ = ar - __uint_as_float(((unsigned)hr)<<16);
  float li_ = ai - __uint_as_float(((unsigned)hi_)<<16);
  *(ushort2*)(mh + a) = make_ushort2(hr, hi_);
  *(ushort2*)(ml + a) = make_ushort2(f2bf(lr_), f2bf(li_));
}

// ---- fused layer: conv+spectral MFMA, direct stores, fused partial DFT
//      (one 128-l chunk per block; partial chunk store, no atomics)
__global__ __launch_bounds__(256) void k_layer(
    const unsigned short* __restrict__ xlc,
    const unsigned short* __restrict__ wfch, const unsigned short* __restrict__ wfcl,
    const unsigned short* __restrict__ wmh, const unsigned short* __restrict__ wml,
    const unsigned short* __restrict__ tif, const unsigned short* __restrict__ tf,
    const float* __restrict__ cb,
    unsigned short* __restrict__ xnh, float* __restrict__ xmout,
    float* __restrict__ dout, int last){
  __shared__ __align__(16) unsigned short ldt[64*128];  // swizzled [c][l-l0]
  int l0 = blockIdx.x * 128; int b = blockIdx.y;
  int tid = threadIdx.x;
  int os = tid >> 6, lane = tid & 63, q = lane >> 4, lr = lane & 15;
  const char* xb = (const char*)xlc + (size_t)b*BST;

  short8 ch_[2], cl_[2], mh_[2], ml_[2];
  #pragma unroll
  for (int ks=0;ks<2;ks++){
    size_t a = ((size_t)((ks*4 + os)*64 + lane))*8;
    ch_[ks] = *(const short8*)(wfch + a);
    cl_[ks] = *(const short8*)(wfcl + a);
    size_t am = ((size_t)(((b*2 + ks)*4 + os)*64 + lane))*8;
    mh_[ks] = *(const short8*)(wmh + am);
    ml_[ks] = *(const short8*)(wml + am);
  }
  f32x4 acc[8];
  #pragma unroll
  for (int ls=0;ls<8;ls++) acc[ls] = (f32x4){0.f,0.f,0.f,0.f};
  int sw = (lr & 7) << 4;
  #pragma unroll
  for (int ks=0;ks<2;ks++){
    int cofs = (64*ks + 16*q) ^ sw;
    #pragma unroll
    for (int ls=0;ls<8;ls++){
      short8 bh = *(const short8*)(xb + (size_t)(l0 + ls*16 + lr)*128 + cofs);
      acc[ls] = __builtin_amdgcn_mfma_f32_16x16x32_bf16(ch_[ks], bh, acc[ls], 0,0,0);
      acc[ls] = __builtin_amdgcn_mfma_f32_16x16x32_bf16(cl_[ks], bh, acc[ls], 0,0,0);
    }
  }
  #pragma unroll
  for (int ks=0;ks<2;ks++){
    #pragma unroll
    for (int ls=0;ls<8;ls++){
      int l = l0 + ls*16 + lr;
      short8 bt = *(const short8*)(tif + ((size_t)((ks*4 + q)*LP + l))*8);
      acc[ls] = __builtin_amdgcn_mfma_f32_16x16x32_bf16(mh_[ks], bt, acc[ls], 0,0,0);
      acc[ls] = __builtin_amdgcn_mfma_f32_16x16x32_bf16(ml_[ks], bt, acc[ls], 0,0,0);
    }
  }
  float bias[4];
  #pragma unroll
  for (int r=0;r<4;r++) bias[r] = cb[os*16 + 4*q + r];

  if (!last){
    int co = os*32 + 8*q;
    char* nb = (char*)xnh + (size_t)b*BST;
    #pragma unroll
    for (int ls=0;ls<8;ls++){
      int lrow = ls*16 + lr; int l = l0 + lrow;
      unsigned short us[4];
      #pragma unroll
      for (int r=0;r<4;r++)
        us[r] = (l < NFFT) ? f2bf(gelu_f(acc[ls][r] + bias[r])) : (unsigned short)0;
      if (l < NFFT){
        unsigned int h0 = (unsigned)us[0] | (((unsigned)us[1])<<16);
        unsigned int h1 = (unsigned)us[2] | (((unsigned)us[3])<<16);
        *(uint2*)(nb + (size_t)l*128 + (co ^ ((lrow&7)<<4))) = make_uint2(h0,h1);
      }
      #pragma unroll
      for (int r=0;r<4;r++){
        int c = os*16 + 4*q + r;
        *(unsigned short*)((char*)ldt + c*256 + ((lrow*2) ^ ((c&7)<<4))) = us[r];
      }
    }
    __syncthreads();
    f32x4 a2[4];
    #pragma unroll
    for (int js=0;js<4;js++) a2[js] = (f32x4){0.f,0.f,0.f,0.f};
    #pragma unroll
    for (int ks=0;ks<4;ks++){
      short8 av = *(const short8*)((char*)ldt + (os*16+lr)*256 + ((ks*64 + 16*q) ^ ((lr&7)<<4)));
      #pragma unroll
      for (int js=0;js<4;js++){
        short8 bv = *(const short8*)(tf + ((size_t)(((blockIdx.x*4 + ks)*4 + js)*64 + lane))*8);
        a2[js] = __builtin_amdgcn_mfma_f32_16x16x32_bf16(av, bv, a2[js], 0,0,0);
      }
    }
    float* pp = xmout + ((size_t)blockIdx.x*64 + b)*4096;
    #pragma unroll
    for (int js=0;js<4;js++){
      #pragma unroll
      for (int r=0;r<4;r++)
        pp[(os*16 + 4*q + r)*64 + js*16 + lr] = a2[js][r];
    }
  } else {
    #pragma unroll
    for (int ls=0;ls<8;ls++){
      int l = l0 + ls*16 + lr;
      if (l < LL){
        #pragma unroll
        for (int r=0;r<4;r++){
          int o = os*16 + 4*q + r;
          dout[((size_t)(b*64 + o))*LL + l] = acc[ls][r] + bias[r];
        }
      }
    }
  }
}

extern "C" void kernel_launch(void* const* d_in, const int* in_sizes, int n_in,
                              void* d_out, int out_size, void* d_ws, size_t ws_size,
                              hipStream_t stream) {
  const float* x   = (const float*)d_in[0];
  const float* lw  = (const float*)d_in[1];
  const float* lb  = (const float*)d_in[2];
  const float* cw  = (const float*)d_in[3];
  const float* cb  = (const float*)d_in[4];
  const float* swr = (const float*)d_in[5];
  const float* swi = (const float*)d_in[6];

  char* ws = (char*)d_ws;
  size_t PL = (size_t)NB*BST;                 // 34,603,008 bytes per plane
  unsigned short* x0lc = (unsigned short*)(ws);
  unsigned short* x1lc = (unsigned short*)(ws + PL);
  unsigned short* tf   = (unsigned short*)(ws + 2*PL);
  unsigned short* tif  = (unsigned short*)(ws + 2*PL + 540672);
  unsigned short* wfch = (unsigned short*)(ws + 2*PL + 2*540672);
  unsigned short* wfcl = (unsigned short*)(ws + 2*PL + 2*540672 + 32768);
  unsigned short* wmh  = (unsigned short*)(ws + 2*PL + 2*540672 + 2*32768);
  unsigned short* wml  = (unsigned short*)(ws + 2*PL + 2*540672 + 2*32768 + 524288);
  float*          xm   = (float*)        (ws + 2*PL + 2*540672 + 2*32768 + 2*524288);
  float*          pA   = xm + 262144;         // 33 x 1MB partial chunks
  float*          pB   = pA + (size_t)PCH*262144;

  k_tables<<<2176, 256,0,stream>>>(cw, tf, tif, wfch, wfcl);
  k_lift2 <<<dim3(LCH,NB),256,0,stream>>>(x, lw, lb, tf, x0lc, pA);

  for (int k=0;k<NRL;k++){
    unsigned short* curlc = (k&1) ? x1lc : x0lc;
    unsigned short* nxtlc = (k&1) ? x0lc : x1lc;
    float* psrc = (k&1) ? pB : pA;
    float* pdst = (k&1) ? pA : pB;
    k_red<<<512, 256,0,stream>>>(psrc, xm);
    k_mix<<<512, 256,0,stream>>>(xm, swr + (size_t)k*131072, swi + (size_t)k*131072, wmh, wml);
    k_layer<<<dim3(LCH,NB),256,0,stream>>>(curlc,
        wfch + (size_t)k*4096, wfcl + (size_t)k*4096, wmh, wml, tif, tf,
        cb + (size_t)k*64, nxtlc, pdst, (float*)d_out, (k==NRL-1) ? 1 : 0);
  }
}

// Round 12
// 255.888 us; speedup vs baseline: 1.1781x; 1.0139x over previous
//
#include <hip/hip_runtime.h>
#include <hip/hip_bf16.h>
#include <math.h>

#define NRL 4
#define LL 4096
#define NFFT 4104
#define LP 4224
#define NB 64
#define WD 64
#define BST (LP*WD*2)        // 540672 bytes per batch plane
#define LCH 33               // l-chunks of 128
#define PCH 33               // partial chunks
#define PI2 6.28318530717958647692f

typedef __attribute__((ext_vector_type(8))) short short8;
typedef __attribute__((ext_vector_type(4))) float f32x4;

__device__ inline unsigned short f2bf(float f){
  unsigned int u = __float_as_uint(f);
  return (unsigned short)((u + 0x7FFFu + ((u>>16)&1u)) >> 16);
}
__device__ inline unsigned pack_bf2(float lo, float hi){
  return (unsigned)f2bf(lo) | (((unsigned)f2bf(hi)) << 16);
}
// tanh-form gelu: |err vs erf-gelu| <= ~5e-4
__device__ inline float gelu_f(float v){
  float v2 = v*v;
  float z = v * fmaf(0.07135481627f, v2, 1.5957691216f);
  float e = __expf(-z);
  return v * __builtin_amdgcn_rcpf(1.0f + e);
}

// ---- one prologue kernel: tf (1056 blocks) | tif (1056) | conv-w frags (64)
__global__ void k_tables(const float* __restrict__ cw,
                         unsigned short* __restrict__ tf,
                         unsigned short* __restrict__ tif,
                         unsigned short* __restrict__ whi, unsigned short* __restrict__ wlo){
  int bid = blockIdx.x;
  if (bid < 1056){
    int idx = bid*256 + threadIdx.x;          // 270336
    int e = idx & 7; int t = idx >> 3;
    int lane = t & 63; int t2 = t >> 6;
    int js = t2 & 3; int ks = t2 >> 2;
    int l = ks*32 + 8*(lane>>4) + e;
    int j = js*16 + (lane & 15);
    int m = j >> 1;
    float v = 0.f;
    if (l < NFFT){
      int r = (m*l) % NFFT;
      float ang = PI2 * ((float)r / (float)NFFT);
      v = (j & 1) ? -__sinf(ang) : __cosf(ang);
    }
    tf[idx] = f2bf(v);
  } else if (bid < 2112){
    int idx = (bid-1056)*256 + threadIdx.x;   // 270336
    int e = idx & 7; int t = idx >> 3;
    int l = t % LP; int rq = t / LP;
    int q = rq & 3; int ks2 = rq >> 2;
    int j2 = ks2*32 + 8*q + e;
    int m = j2 >> 1;
    float v = 0.f;
    if (l < NFFT){
      int r = (m*l) % NFFT;
      float ang = PI2 * ((float)r / (float)NFFT);
      float inv = 1.0f/(float)NFFT;
      v = (j2 & 1) ? (-2.f*inv*__sinf(ang)) : ((m==0?inv:2.f*inv)*__cosf(ang));
    }
    tif[idx] = f2bf(v);
  } else {
    int idx = (bid-2112)*256 + threadIdx.x;   // 16384
    int e = idx & 7; int lane = (idx>>3)&63; int os = (idx>>9)&3;
    int ks2 = (idx>>11)&1; int ly = idx>>12;
    int k = ks2*32 + 8*(lane>>4) + e;
    int o = os*16 + (lane&15);
    float v = cw[((size_t)(ly*64 + o))*64 + k];
    unsigned short h = f2bf(v);
    float lo = v - __uint_as_float(((unsigned)h)<<16);
    whi[idx] = h; wlo[idx] = f2bf(lo);
  }
}

// ---- fused lift: lifted x -> lc plane + LDS transpose -> partial DFT chunk
__global__ __launch_bounds__(256) void k_lift2(const float* __restrict__ x,
    const float* __restrict__ lw, const float* __restrict__ lb,
    const unsigned short* __restrict__ tf,
    unsigned short* __restrict__ xh, unsigned* __restrict__ pout){
  __shared__ __align__(16) unsigned short ldt[64*128];  // swizzled [c][l-l0]
  __shared__ float xs[128];
  int l0 = blockIdx.x*128; int b = blockIdx.y;
  int tid = threadIdx.x;
  int os = tid >> 6, lane = tid & 63, q = lane >> 4, lr = lane & 15;
  if (tid < 32){
    float4 v = make_float4(0.f,0.f,0.f,0.f);
    int l = l0 + tid*4;
    if (l < LL) v = *(const float4*)(x + (size_t)b*LL + l);
    *(float4*)(xs + tid*4) = v;
  }
  __syncthreads();
  float w0[4], w1[4], bb[4];
  #pragma unroll
  for (int r=0;r<4;r++){
    int c = os*16 + 4*q + r;
    w0[r] = lw[2*c]; w1[r] = lw[2*c+1]; bb[r] = lb[c];
  }
  char* nb = (char*)xh + (size_t)b*BST;
  int co = os*32 + 8*q;
  #pragma unroll
  for (int ls=0;ls<8;ls++){
    int lrow = ls*16 + lr; int l = l0 + lrow;
    float g = (float)l * (1.0f/4095.0f);
    unsigned short us[4];
    #pragma unroll
    for (int r=0;r<4;r++){
      float v = (l < LL) ? fmaf(w0[r], xs[lrow], fmaf(w1[r], g, bb[r])) : 0.f;
      us[r] = f2bf(v);
    }
    unsigned int h0 = (unsigned)us[0] | (((unsigned)us[1])<<16);
    unsigned int h1 = (unsigned)us[2] | (((unsigned)us[3])<<16);
    *(uint2*)(nb + (size_t)l*128 + (co ^ ((lrow&7)<<4))) = make_uint2(h0,h1);
    #pragma unroll
    for (int r=0;r<4;r++){
      int c = os*16 + 4*q + r;
      *(unsigned short*)((char*)ldt + c*256 + ((lrow*2) ^ ((c&7)<<4))) = us[r];
    }
  }
  __syncthreads();
  f32x4 a2[4];
  #pragma unroll
  for (int js=0;js<4;js++) a2[js] = (f32x4){0.f,0.f,0.f,0.f};
  #pragma unroll
  for (int ks=0;ks<4;ks++){
    short8 av = *(const short8*)((char*)ldt + (os*16+lr)*256 + ((ks*64 + 16*q) ^ ((lr&7)<<4)));
    #pragma unroll
    for (int js=0;js<4;js++){
      short8 bv = *(const short8*)(tf + ((size_t)(((blockIdx.x*4 + ks)*4 + js)*64 + lane))*8);
      a2[js] = __builtin_amdgcn_mfma_f32_16x16x32_bf16(av, bv, a2[js], 0,0,0);
    }
  }
  // bf16-pair partial store: [chunk][b][pair][os][q][js][lr] u32
  unsigned* pp = pout + ((size_t)blockIdx.x*64 + b)*2048 + os*256 + q*64 + lr;
  #pragma unroll
  for (int js=0;js<4;js++){
    pp[js*16]        = pack_bf2(a2[js][0], a2[js][1]);
    pp[1024 + js*16] = pack_bf2(a2[js][2], a2[js][3]);
  }
}

// ---- reduce 33 bf16-pair chunks -> xm f32 [b][c][j] (512 blocks)
__global__ void k_red(const unsigned* __restrict__ pb, float* __restrict__ xm){
  int t = blockIdx.x*256 + threadIdx.x;       // 131072 = 64b * 2048
  int b = t >> 11, s = t & 2047;
  int pair = s >> 10, rem = s & 1023;
  int os = rem >> 8, q = (rem >> 6) & 3, js = (rem >> 4) & 3, lr = s & 15;
  int c = os*16 + q*4 + pair*2;
  int j = js*16 + lr;
  float slo = 0.f, shi = 0.f;
  #pragma unroll 3
  for (int p=0;p<PCH;p++){
    unsigned v = pb[(size_t)p*131072 + t];
    slo += __uint_as_float(v << 16);
    shi += __uint_as_float(v & 0xFFFF0000u);
  }
  xm[(size_t)b*4096 + c*64 + j]     = slo;
  xm[(size_t)b*4096 + (c+1)*64 + j] = shi;
}

// ---- mode mix -> om A-operand frags [b][ks2 2][os 4][lane 64][e 8] hi/lo
__global__ void k_mix(const float* __restrict__ xm, const float* __restrict__ wr,
                      const float* __restrict__ wi,
                      unsigned short* __restrict__ mh, unsigned short* __restrict__ ml){
  int idx = blockIdx.x*256 + threadIdx.x;     // 131072
  int m = idx & 31, o = (idx>>5)&63, b = idx>>11;
  const float* xp = xm + ((size_t)(b*64))*64 + 2*m;
  float ar=0.f, ai=0.f;
  for (int i=0;i<64;i++){
    float xr = xp[i*64], xi = xp[i*64+1];
    float wrv = wr[((size_t)(i*64 + o))*32 + m];
    float wiv = wi[((size_t)(i*64 + o))*32 + m];
    ar = fmaf(xr,wrv,ar); ar = fmaf(-xi,wiv,ar);
    ai = fmaf(xr,wiv,ai); ai = fmaf(xi,wrv,ai);
  }
  int j2 = 2*m;
  int ks2 = j2 >> 5, rem = j2 & 31, q = rem >> 3, e = rem & 7;
  int lane = q*16 + (o & 15), os = o >> 4;
  size_t a = ((size_t)(((b*2 + ks2)*4 + os)*64 + lane))*8 + e;
  unsigned short hr = f2bf(ar), hi_ = f2bf(ai);
  float lr_ = ar - __uint_as_float(((unsigned)hr)<<16);
  float li_ = ai - __uint_as_float(((unsigned)hi_)<<16);
  *(ushort2*)(mh + a) = make_ushort2(hr, hi_);
  *(ushort2*)(ml + a) = make_ushort2(f2bf(lr_), f2bf(li_));
}

// ---- fused layer: conv+spectral MFMA, direct stores, fused partial DFT
//      (one 128-l chunk per block; bf16-pair partial store, no atomics)
__global__ __launch_bounds__(256) void k_layer(
    const unsigned short* __restrict__ xlc,
    const unsigned short* __restrict__ wfch, const unsigned short* __restrict__ wfcl,
    const unsigned short* __restrict__ wmh, const unsigned short* __restrict__ wml,
    const unsigned short* __restrict__ tif, const unsigned short* __restrict__ tf,
    const float* __restrict__ cb,
    unsigned short* __restrict__ xnh, unsigned* __restrict__ pout,
    float* __restrict__ dout, int last){
  __shared__ __align__(16) unsigned short ldt[64*128];  // swizzled [c][l-l0]
  int l0 = blockIdx.x * 128; int b = blockIdx.y;
  int tid = threadIdx.x;
  int os = tid >> 6, lane = tid & 63, q = lane >> 4, lr = lane & 15;
  const char* xb = (const char*)xlc + (size_t)b*BST;

  short8 ch_[2], cl_[2], mh_[2], ml_[2];
  #pragma unroll
  for (int ks=0;ks<2;ks++){
    size_t a = ((size_t)((ks*4 + os)*64 + lane))*8;
    ch_[ks] = *(const short8*)(wfch + a);
    cl_[ks] = *(const short8*)(wfcl + a);
    size_t am = ((size_t)(((b*2 + ks)*4 + os)*64 + lane))*8;
    mh_[ks] = *(const short8*)(wmh + am);
    ml_[ks] = *(const short8*)(wml + am);
  }
  f32x4 acc[8];
  #pragma unroll
  for (int ls=0;ls<8;ls++) acc[ls] = (f32x4){0.f,0.f,0.f,0.f};
  int sw = (lr & 7) << 4;
  #pragma unroll
  for (int ks=0;ks<2;ks++){
    int cofs = (64*ks + 16*q) ^ sw;
    #pragma unroll
    for (int ls=0;ls<8;ls++){
      short8 bh = *(const short8*)(xb + (size_t)(l0 + ls*16 + lr)*128 + cofs);
      acc[ls] = __builtin_amdgcn_mfma_f32_16x16x32_bf16(ch_[ks], bh, acc[ls], 0,0,0);
      acc[ls] = __builtin_amdgcn_mfma_f32_16x16x32_bf16(cl_[ks], bh, acc[ls], 0,0,0);
    }
  }
  #pragma unroll
  for (int ks=0;ks<2;ks++){
    #pragma unroll
    for (int ls=0;ls<8;ls++){
      int l = l0 + ls*16 + lr;
      short8 bt = *(const short8*)(tif + ((size_t)((ks*4 + q)*LP + l))*8);
      acc[ls] = __builtin_amdgcn_mfma_f32_16x16x32_bf16(mh_[ks], bt, acc[ls], 0,0,0);
      acc[ls] = __builtin_amdgcn_mfma_f32_16x16x32_bf16(ml_[ks], bt, acc[ls], 0,0,0);
    }
  }
  float bias[4];
  #pragma unroll
  for (int r=0;r<4;r++) bias[r] = cb[os*16 + 4*q + r];

  if (!last){
    int co = os*32 + 8*q;
    char* nb = (char*)xnh + (size_t)b*BST;
    #pragma unroll
    for (int ls=0;ls<8;ls++){
      int lrow = ls*16 + lr; int l = l0 + lrow;
      unsigned short us[4];
      #pragma unroll
      for (int r=0;r<4;r++)
        us[r] = (l < NFFT) ? f2bf(gelu_f(acc[ls][r] + bias[r])) : (unsigned short)0;
      if (l < NFFT){
        unsigned int h0 = (unsigned)us[0] | (((unsigned)us[1])<<16);
        unsigned int h1 = (unsigned)us[2] | (((unsigned)us[3])<<16);
        *(uint2*)(nb + (size_t)l*128 + (co ^ ((lrow&7)<<4))) = make_uint2(h0,h1);
      }
      #pragma unroll
      for (int r=0;r<4;r++){
        int c = os*16 + 4*q + r;
        *(unsigned short*)((char*)ldt + c*256 + ((lrow*2) ^ ((c&7)<<4))) = us[r];
      }
    }
    __syncthreads();
    f32x4 a2[4];
    #pragma unroll
    for (int js=0;js<4;js++) a2[js] = (f32x4){0.f,0.f,0.f,0.f};
    #pragma unroll
    for (int ks=0;ks<4;ks++){
      short8 av = *(const short8*)((char*)ldt + (os*16+lr)*256 + ((ks*64 + 16*q) ^ ((lr&7)<<4)));
      #pragma unroll
      for (int js=0;js<4;js++){
        short8 bv = *(const short8*)(tf + ((size_t)(((blockIdx.x*4 + ks)*4 + js)*64 + lane))*8);
        a2[js] = __builtin_amdgcn_mfma_f32_16x16x32_bf16(av, bv, a2[js], 0,0,0);
      }
    }
    unsigned* pp = pout + ((size_t)blockIdx.x*64 + b)*2048 + os*256 + q*64 + lr;
    #pragma unroll
    for (int js=0;js<4;js++){
      pp[js*16]        = pack_bf2(a2[js][0], a2[js][1]);
      pp[1024 + js*16] = pack_bf2(a2[js][2], a2[js][3]);
    }
  } else {
    #pragma unroll
    for (int ls=0;ls<8;ls++){
      int l = l0 + ls*16 + lr;
      if (l < LL){
        #pragma unroll
        for (int r=0;r<4;r++){
          int o = os*16 + 4*q + r;
          dout[((size_t)(b*64 + o))*LL + l] = acc[ls][r] + bias[r];
        }
      }
    }
  }
}

extern "C" void kernel_launch(void* const* d_in, const int* in_sizes, int n_in,
                              void* d_out, int out_size, void* d_ws, size_t ws_size,
                              hipStream_t stream) {
  const float* x   = (const float*)d_in[0];
  const float* lw  = (const float*)d_in[1];
  const float* lb  = (const float*)d_in[2];
  const float* cw  = (const float*)d_in[3];
  const float* cb  = (const float*)d_in[4];
  const float* swr = (const float*)d_in[5];
  const float* swi = (const float*)d_in[6];

  char* ws = (char*)d_ws;
  size_t PL = (size_t)NB*BST;                 // 34,603,008 bytes per plane
  unsigned short* x0lc = (unsigned short*)(ws);
  unsigned short* x1lc = (unsigned short*)(ws + PL);
  unsigned short* tf   = (unsigned short*)(ws + 2*PL);
  unsigned short* tif  = (unsigned short*)(ws + 2*PL + 540672);
  unsigned short* wfch = (unsigned short*)(ws + 2*PL + 2*540672);
  unsigned short* wfcl = (unsigned short*)(ws + 2*PL + 2*540672 + 32768);
  unsigned short* wmh  = (unsigned short*)(ws + 2*PL + 2*540672 + 2*32768);
  unsigned short* wml  = (unsigned short*)(ws + 2*PL + 2*540672 + 2*32768 + 524288);
  float*          xm   = (float*)        (ws + 2*PL + 2*540672 + 2*32768 + 2*524288);
  unsigned*       pA   = (unsigned*)(xm + 262144);        // 33 x 512KB bf16-pair chunks
  unsigned*       pB   = pA + (size_t)PCH*131072;

  k_tables<<<2176, 256,0,stream>>>(cw, tf, tif, wfch, wfcl);
  k_lift2 <<<dim3(LCH,NB),256,0,stream>>>(x, lw, lb, tf, x0lc, pA);

  for (int k=0;k<NRL;k++){
    unsigned short* curlc = (k&1) ? x1lc : x0lc;
    unsigned short* nxtlc = (k&1) ? x0lc : x1lc;
    unsigned* psrc = (k&1) ? pB : pA;
    unsigned* pdst = (k&1) ? pA : pB;
    k_red<<<512, 256,0,stream>>>(psrc, xm);
    k_mix<<<512, 256,0,stream>>>(xm, swr + (size_t)k*131072, swi + (size_t)k*131072, wmh, wml);
    k_layer<<<dim3(LCH,NB),256,0,stream>>>(curlc,
        wfch + (size_t)k*4096, wfcl + (size_t)k*4096, wmh, wml, tif, tf,
        cb + (size_t)k*64, nxtlc, pdst, (float*)d_out, (k==NRL-1) ? 1 : 0);
  }
}

// Round 13
// 234.567 us; speedup vs baseline: 1.2852x; 1.0909x over previous
//
#include <hip/hip_runtime.h>
#include <hip/hip_bf16.h>
#include <math.h>

#define NRL 4
#define LL 4096
#define NFFT 4104
#define LP 4224
#define NB 64
#define WD 64
#define BST (LP*WD*2)        // 540672 bytes per batch plane (tiled layout)
#define LCH 33               // l-chunks of 128
#define PCH 33               // partial chunks
#define NLB 264              // l-tiles of 16 (LP/16)
#define PI2 6.28318530717958647692f

typedef __attribute__((ext_vector_type(8))) short short8;
typedef __attribute__((ext_vector_type(4))) float f32x4;

__device__ inline unsigned short f2bf(float f){
  unsigned int u = __float_as_uint(f);
  return (unsigned short)((u + 0x7FFFu + ((u>>16)&1u)) >> 16);
}
__device__ inline unsigned pack_bf2(float lo, float hi){
  return (unsigned)f2bf(lo) | (((unsigned)f2bf(hi)) << 16);
}
// tanh-form gelu: |err vs erf-gelu| <= ~5e-4
__device__ inline float gelu_f(float v){
  float v2 = v*v;
  float z = v * fmaf(0.07135481627f, v2, 1.5957691216f);
  float e = __expf(-z);
  return v * __builtin_amdgcn_rcpf(1.0f + e);
}

// x-plane tiled layout: per b, [lblk 264][cks 2][lane 64][e 8] bf16 (1KB tiles)
// tile(lblk,cks) holds y[c = cks*32 + 8*(lane>>4) + e][l = lblk*16 + (lane&15)]

// ---- one prologue kernel: tf (1056 blocks) | tif tiled (1056) | conv-w frags (64)
__global__ void k_tables(const float* __restrict__ cw,
                         unsigned short* __restrict__ tf,
                         unsigned short* __restrict__ tif,
                         unsigned short* __restrict__ whi, unsigned short* __restrict__ wlo){
  int bid = blockIdx.x;
  if (bid < 1056){
    int idx = bid*256 + threadIdx.x;          // 270336
    int e = idx & 7; int t = idx >> 3;
    int lane = t & 63; int t2 = t >> 6;
    int js = t2 & 3; int ks = t2 >> 2;
    int l = ks*32 + 8*(lane>>4) + e;
    int j = js*16 + (lane & 15);
    int m = j >> 1;
    float v = 0.f;
    if (l < NFFT){
      int r = (m*l) % NFFT;
      float ang = PI2 * ((float)r / (float)NFFT);
      v = (j & 1) ? -__sinf(ang) : __cosf(ang);
    }
    tf[idx] = f2bf(v);
  } else if (bid < 2112){
    // tif tiled: idx = ((ks*264 + lblk)*64 + lane)*8 + e
    int idx = (bid-1056)*256 + threadIdx.x;   // 270336
    int e = idx & 7; int t = idx >> 3;
    int lane = t & 63; int u = t >> 6;
    int lblk = u % NLB; int ks = u / NLB;
    int j2 = ks*32 + 8*(lane>>4) + e;
    int l = lblk*16 + (lane & 15);
    int m = j2 >> 1;
    float v = 0.f;
    if (l < NFFT){
      int r = (m*l) % NFFT;
      float ang = PI2 * ((float)r / (float)NFFT);
      float inv = 1.0f/(float)NFFT;
      v = (j2 & 1) ? (-2.f*inv*__sinf(ang)) : ((m==0?inv:2.f*inv)*__cosf(ang));
    }
    tif[idx] = f2bf(v);
  } else {
    int idx = (bid-2112)*256 + threadIdx.x;   // 16384
    int e = idx & 7; int lane = (idx>>3)&63; int os = (idx>>9)&3;
    int ks2 = (idx>>11)&1; int ly = idx>>12;
    int k = ks2*32 + 8*(lane>>4) + e;
    int o = os*16 + (lane&15);
    float v = cw[((size_t)(ly*64 + o))*64 + k];
    unsigned short h = f2bf(v);
    float lo = v - __uint_as_float(((unsigned)h)<<16);
    whi[idx] = h; wlo[idx] = f2bf(lo);
  }
}

// ---- fused lift: lifted x -> tiled plane + LDS transpose -> partial DFT chunk
__global__ __launch_bounds__(256) void k_lift2(const float* __restrict__ x,
    const float* __restrict__ lw, const float* __restrict__ lb,
    const unsigned short* __restrict__ tf,
    unsigned short* __restrict__ xh, unsigned* __restrict__ pout){
  __shared__ __align__(16) unsigned short ldt[64*128];  // swizzled [c][l-l0]
  __shared__ float xs[128];
  int l0 = blockIdx.x*128; int b = blockIdx.y;
  int tid = threadIdx.x;
  int os = tid >> 6, lane = tid & 63, q = lane >> 4, lr = lane & 15;
  if (tid < 32){
    float4 v = make_float4(0.f,0.f,0.f,0.f);
    int l = l0 + tid*4;
    if (l < LL) v = *(const float4*)(x + (size_t)b*LL + l);
    *(float4*)(xs + tid*4) = v;
  }
  __syncthreads();
  float w0[4], w1[4], bb[4];
  #pragma unroll
  for (int r=0;r<4;r++){
    int c = os*16 + 4*q + r;
    w0[r] = lw[2*c]; w1[r] = lw[2*c+1]; bb[r] = lb[c];
  }
  char* nb = (char*)xh + (size_t)b*BST;
  int cks = os >> 1;
  int qp  = (os & 1)*2 + (q >> 1);
  int e0  = (q & 1)*4;
  #pragma unroll
  for (int ls=0;ls<8;ls++){
    int lrow = ls*16 + lr; int l = l0 + lrow;
    float g = (float)l * (1.0f/4095.0f);
    unsigned short us[4];
    #pragma unroll
    for (int r=0;r<4;r++){
      float v = (l < LL) ? fmaf(w0[r], xs[lrow], fmaf(w1[r], g, bb[r])) : 0.f;
      us[r] = f2bf(v);
    }
    unsigned int h0 = (unsigned)us[0] | (((unsigned)us[1])<<16);
    unsigned int h1 = (unsigned)us[2] | (((unsigned)us[3])<<16);
    int lblk = blockIdx.x*8 + ls;
    *(uint2*)(nb + ((size_t)(lblk*2 + cks))*1024 + (qp*16 + lr)*16 + e0*2) = make_uint2(h0,h1);
    #pragma unroll
    for (int r=0;r<4;r++){
      int c = os*16 + 4*q + r;
      *(unsigned short*)((char*)ldt + c*256 + ((lrow*2) ^ ((c&7)<<4))) = us[r];
    }
  }
  __syncthreads();
  f32x4 a2[4];
  #pragma unroll
  for (int js=0;js<4;js++) a2[js] = (f32x4){0.f,0.f,0.f,0.f};
  #pragma unroll
  for (int ks=0;ks<4;ks++){
    short8 av = *(const short8*)((char*)ldt + (os*16+lr)*256 + ((ks*64 + 16*q) ^ ((lr&7)<<4)));
    #pragma unroll
    for (int js=0;js<4;js++){
      short8 bv = *(const short8*)(tf + ((size_t)(((blockIdx.x*4 + ks)*4 + js)*64 + lane))*8);
      a2[js] = __builtin_amdgcn_mfma_f32_16x16x32_bf16(av, bv, a2[js], 0,0,0);
    }
  }
  // bf16-pair partial store: [chunk][b][pair][os][q][js][lr] u32
  unsigned* pp = pout + ((size_t)blockIdx.x*64 + b)*2048 + os*256 + q*64 + lr;
  #pragma unroll
  for (int js=0;js<4;js++){
    pp[js*16]        = pack_bf2(a2[js][0], a2[js][1]);
    pp[1024 + js*16] = pack_bf2(a2[js][2], a2[js][3]);
  }
}

// ---- reduce 33 bf16-pair chunks -> xm f32 [b][c][j] (512 blocks)
__global__ void k_red(const unsigned* __restrict__ pb, float* __restrict__ xm){
  int t = blockIdx.x*256 + threadIdx.x;       // 131072 = 64b * 2048
  int b = t >> 11, s = t & 2047;
  int pair = s >> 10, rem = s & 1023;
  int os = rem >> 8, q = (rem >> 6) & 3, js = (rem >> 4) & 3, lr = s & 15;
  int c = os*16 + q*4 + pair*2;
  int j = js*16 + lr;
  float slo = 0.f, shi = 0.f;
  #pragma unroll 3
  for (int p=0;p<PCH;p++){
    unsigned v = pb[(size_t)p*131072 + t];
    slo += __uint_as_float(v << 16);
    shi += __uint_as_float(v & 0xFFFF0000u);
  }
  xm[(size_t)b*4096 + c*64 + j]     = slo;
  xm[(size_t)b*4096 + (c+1)*64 + j] = shi;
}

// ---- mode mix -> om A-operand frags [b][ks2 2][os 4][lane 64][e 8] hi/lo
__global__ void k_mix(const float* __restrict__ xm, const float* __restrict__ wr,
                      const float* __restrict__ wi,
                      unsigned short* __restrict__ mh, unsigned short* __restrict__ ml){
  int idx = blockIdx.x*256 + threadIdx.x;     // 131072
  int m = idx & 31, o = (idx>>5)&63, b = idx>>11;
  const float* xp = xm + ((size_t)(b*64))*64 + 2*m;
  float ar=0.f, ai=0.f;
  for (int i=0;i<64;i++){
    float xr = xp[i*64], xi = xp[i*64+1];
    float wrv = wr[((size_t)(i*64 + o))*32 + m];
    float wiv = wi[((size_t)(i*64 + o))*32 + m];
    ar = fmaf(xr,wrv,ar); ar = fmaf(-xi,wiv,ar);
    ai = fmaf(xr,wiv,ai); ai = fmaf(xi,wrv,ai);
  }
  int j2 = 2*m;
  int ks2 = j2 >> 5, rem = j2 & 31, q = rem >> 3, e = rem & 7;
  int lane = q*16 + (o & 15), os = o >> 4;
  size_t a = ((size_t)(((b*2 + ks2)*4 + os)*64 + lane))*8 + e;
  unsigned short hr = f2bf(ar), hi_ = f2bf(ai);
  float lr_ = ar - __uint_as_float(((unsigned)hr)<<16);
  float li_ = ai - __uint_as_float(((unsigned)hi_)<<16);
  *(ushort2*)(mh + a) = make_ushort2(hr, hi_);
  *(ushort2*)(ml + a) = make_ushort2(f2bf(lr_), f2bf(li_));
}

// ---- fused layer: tiled-plane coalesced B-frag loads, conv+spectral MFMA,
//      tiled stores, fused partial DFT (bf16-pair partial store)
__global__ __launch_bounds__(256) void k_layer(
    const unsigned short* __restrict__ xlc,
    const unsigned short* __restrict__ wfch, const unsigned short* __restrict__ wfcl,
    const unsigned short* __restrict__ wmh, const unsigned short* __restrict__ wml,
    const unsigned short* __restrict__ tif, const unsigned short* __restrict__ tf,
    const float* __restrict__ cb,
    unsigned short* __restrict__ xnh, unsigned* __restrict__ pout,
    float* __restrict__ dout, int last){
  __shared__ __align__(16) unsigned short ldt[64*128];  // swizzled [c][l-l0]
  int l0 = blockIdx.x * 128; int b = blockIdx.y;
  int tid = threadIdx.x;
  int os = tid >> 6, lane = tid & 63, q = lane >> 4, lr = lane & 15;
  const char* xb = (const char*)xlc + (size_t)b*BST;

  short8 ch_[2], cl_[2], mh_[2], ml_[2];
  #pragma unroll
  for (int ks=0;ks<2;ks++){
    size_t a = ((size_t)((ks*4 + os)*64 + lane))*8;
    ch_[ks] = *(const short8*)(wfch + a);
    cl_[ks] = *(const short8*)(wfcl + a);
    size_t am = ((size_t)(((b*2 + ks)*4 + os)*64 + lane))*8;
    mh_[ks] = *(const short8*)(wmh + am);
    ml_[ks] = *(const short8*)(wml + am);
  }
  f32x4 acc[8];
  #pragma unroll
  for (int ls=0;ls<8;ls++) acc[ls] = (f32x4){0.f,0.f,0.f,0.f};
  #pragma unroll
  for (int ks=0;ks<2;ks++){
    #pragma unroll
    for (int ls=0;ls<8;ls++){
      short8 bh = *(const short8*)(xb + ((size_t)((blockIdx.x*8 + ls)*2 + ks))*1024 + lane*16);
      acc[ls] = __builtin_amdgcn_mfma_f32_16x16x32_bf16(ch_[ks], bh, acc[ls], 0,0,0);
      acc[ls] = __builtin_amdgcn_mfma_f32_16x16x32_bf16(cl_[ks], bh, acc[ls], 0,0,0);
    }
  }
  #pragma unroll
  for (int ks=0;ks<2;ks++){
    #pragma unroll
    for (int ls=0;ls<8;ls++){
      short8 bt = *(const short8*)(tif + ((size_t)((ks*NLB + blockIdx.x*8 + ls)*64 + lane))*8);
      acc[ls] = __builtin_amdgcn_mfma_f32_16x16x32_bf16(mh_[ks], bt, acc[ls], 0,0,0);
      acc[ls] = __builtin_amdgcn_mfma_f32_16x16x32_bf16(ml_[ks], bt, acc[ls], 0,0,0);
    }
  }
  float bias[4];
  #pragma unroll
  for (int r=0;r<4;r++) bias[r] = cb[os*16 + 4*q + r];

  if (!last){
    char* nb = (char*)xnh + (size_t)b*BST;
    int cks = os >> 1;
    int qp  = (os & 1)*2 + (q >> 1);
    int e0  = (q & 1)*4;
    #pragma unroll
    for (int ls=0;ls<8;ls++){
      int lrow = ls*16 + lr; int l = l0 + lrow;
      unsigned short us[4];
      #pragma unroll
      for (int r=0;r<4;r++)
        us[r] = (l < NFFT) ? f2bf(gelu_f(acc[ls][r] + bias[r])) : (unsigned short)0;
      unsigned int h0 = (unsigned)us[0] | (((unsigned)us[1])<<16);
      unsigned int h1 = (unsigned)us[2] | (((unsigned)us[3])<<16);
      int lblk = blockIdx.x*8 + ls;
      *(uint2*)(nb + ((size_t)(lblk*2 + cks))*1024 + (qp*16 + lr)*16 + e0*2) = make_uint2(h0,h1);
      #pragma unroll
      for (int r=0;r<4;r++){
        int c = os*16 + 4*q + r;
        *(unsigned short*)((char*)ldt + c*256 + ((lrow*2) ^ ((c&7)<<4))) = us[r];
      }
    }
    __syncthreads();
    f32x4 a2[4];
    #pragma unroll
    for (int js=0;js<4;js++) a2[js] = (f32x4){0.f,0.f,0.f,0.f};
    #pragma unroll
    for (int ks=0;ks<4;ks++){
      short8 av = *(const short8*)((char*)ldt + (os*16+lr)*256 + ((ks*64 + 16*q) ^ ((lr&7)<<4)));
      #pragma unroll
      for (int js=0;js<4;js++){
        short8 bv = *(const short8*)(tf + ((size_t)(((blockIdx.x*4 + ks)*4 + js)*64 + lane))*8);
        a2[js] = __builtin_amdgcn_mfma_f32_16x16x32_bf16(av, bv, a2[js], 0,0,0);
      }
    }
    unsigned* pp = pout + ((size_t)blockIdx.x*64 + b)*2048 + os*256 + q*64 + lr;
    #pragma unroll
    for (int js=0;js<4;js++){
      pp[js*16]        = pack_bf2(a2[js][0], a2[js][1]);
      pp[1024 + js*16] = pack_bf2(a2[js][2], a2[js][3]);
    }
  } else {
    #pragma unroll
    for (int ls=0;ls<8;ls++){
      int l = l0 + ls*16 + lr;
      if (l < LL){
        #pragma unroll
        for (int r=0;r<4;r++){
          int o = os*16 + 4*q + r;
          dout[((size_t)(b*64 + o))*LL + l] = acc[ls][r] + bias[r];
        }
      }
    }
  }
}

extern "C" void kernel_launch(void* const* d_in, const int* in_sizes, int n_in,
                              void* d_out, int out_size, void* d_ws, size_t ws_size,
                              hipStream_t stream) {
  const float* x   = (const float*)d_in[0];
  const float* lw  = (const float*)d_in[1];
  const float* lb  = (const float*)d_in[2];
  const float* cw  = (const float*)d_in[3];
  const float* cb  = (const float*)d_in[4];
  const float* swr = (const float*)d_in[5];
  const float* swi = (const float*)d_in[6];

  char* ws = (char*)d_ws;
  size_t PL = (size_t)NB*BST;                 // 34,603,008 bytes per plane
  unsigned short* x0lc = (unsigned short*)(ws);
  unsigned short* x1lc = (unsigned short*)(ws + PL);
  unsigned short* tf   = (unsigned short*)(ws + 2*PL);
  unsigned short* tif  = (unsigned short*)(ws + 2*PL + 540672);
  unsigned short* wfch = (unsigned short*)(ws + 2*PL + 2*540672);
  unsigned short* wfcl = (unsigned short*)(ws + 2*PL + 2*540672 + 32768);
  unsigned short* wmh  = (unsigned short*)(ws + 2*PL + 2*540672 + 2*32768);
  unsigned short* wml  = (unsigned short*)(ws + 2*PL + 2*540672 + 2*32768 + 524288);
  float*          xm   = (float*)        (ws + 2*PL + 2*540672 + 2*32768 + 2*524288);
  unsigned*       pA   = (unsigned*)(xm + 262144);        // 33 x 512KB bf16-pair chunks
  unsigned*       pB   = pA + (size_t)PCH*131072;

  k_tables<<<2176, 256,0,stream>>>(cw, tf, tif, wfch, wfcl);
  k_lift2 <<<dim3(LCH,NB),256,0,stream>>>(x, lw, lb, tf, x0lc, pA);

  for (int k=0;k<NRL;k++){
    unsigned short* curlc = (k&1) ? x1lc : x0lc;
    unsigned short* nxtlc = (k&1) ? x0lc : x1lc;
    unsigned* psrc = (k&1) ? pB : pA;
    unsigned* pdst = (k&1) ? pA : pB;
    k_red<<<512, 256,0,stream>>>(psrc, xm);
    k_mix<<<512, 256,0,stream>>>(xm, swr + (size_t)k*131072, swi + (size_t)k*131072, wmh, wml);
    k_layer<<<dim3(LCH,NB),256,0,stream>>>(curlc,
        wfch + (size_t)k*4096, wfcl + (size_t)k*4096, wmh, wml, tif, tf,
        cb + (size_t)k*64, nxtlc, pdst, (float*)d_out, (k==NRL-1) ? 1 : 0);
  }
}